// Round 4
// baseline (163.126 us; speedup 1.0000x reference)
//
#include <hip/hip_runtime.h>

// ---------------------------------------------------------------------------
// FakeFusedMoE: E=8, H=1024, F=1024, top-2, N=2048 tokens (4096 routed rows).
// Sparse grouped-GEMM MoE, bf16 MFMA. 2-phase pipelined GEMMs:
//   - dbuf LDS, ONE barrier per K-step
//   - A (bf16) via global_load_lds, pre-swizzled source, issued 1 step early
//   - B (fp32 weights) reg-staged 1 step early, cvt->bf16 AFTER the MFMA
//     phase (T14 split) so LDS holds bf16 (half the read traffic of R2)
// ---------------------------------------------------------------------------

#define NTOK   2048
#define HDIM   1024
#define FDIM   1024
#define NEXP   8
#define NKROWS 4096
#define MAXTILES 40   // sum ceil(n_e/128) <= 39

typedef __attribute__((ext_vector_type(8))) __bf16 bf16x8;
typedef __attribute__((ext_vector_type(4))) float  floatx4;

__device__ __forceinline__ unsigned short f2bf(float x) {
    unsigned int u = __builtin_bit_cast(unsigned int, x);
    u += 0x7FFFu + ((u >> 16) & 1u);
    return (unsigned short)(u >> 16);
}

__device__ __forceinline__ float bf2f(unsigned short v) {
    unsigned int u = (unsigned int)v << 16;
    return __builtin_bit_cast(float, u);
}

__device__ __forceinline__ uint4 pack8(float4 a, float4 b) {
    uint4 o;
    o.x = (unsigned)f2bf(a.x) | ((unsigned)f2bf(a.y) << 16);
    o.y = (unsigned)f2bf(a.z) | ((unsigned)f2bf(a.w) << 16);
    o.z = (unsigned)f2bf(b.x) | ((unsigned)f2bf(b.y) << 16);
    o.w = (unsigned)f2bf(b.z) | ((unsigned)f2bf(b.w) << 16);
    return o;
}

// async global->LDS, 16B/lane; LDS dest = wave-uniform base + lane*16
__device__ __forceinline__ void dma16(const void* g, void* l) {
    __builtin_amdgcn_global_load_lds(
        (const __attribute__((address_space(1))) unsigned int*)g,
        (__attribute__((address_space(3))) unsigned int*)l, 16, 0, 0);
}

// ---------------------------------------------------------------------------
// Router fused with fp32->bf16 hidden conversion. One wave per token.
__global__ __launch_bounds__(256) void k_router(
    const float* __restrict__ h, const float* __restrict__ rw,
    unsigned short* __restrict__ hbf,
    int* __restrict__ topk_idx, float* __restrict__ topk_w)
{
    const int lane = threadIdx.x & 63;
    const int wave = threadIdx.x >> 6;
    const int n = blockIdx.x * 4 + wave;

    const float4* hp = reinterpret_cast<const float4*>(h + (size_t)n * HDIM);
    uint2* hb = reinterpret_cast<uint2*>(hbf + (size_t)n * HDIM);
    float acc[NEXP];
#pragma unroll
    for (int e = 0; e < NEXP; ++e) acc[e] = 0.f;

#pragma unroll
    for (int i0 = 0; i0 < HDIM / 4; i0 += 64) {
        float4 hv = hp[i0 + lane];
        uint2 o;
        o.x = (unsigned)f2bf(hv.x) | ((unsigned)f2bf(hv.y) << 16);
        o.y = (unsigned)f2bf(hv.z) | ((unsigned)f2bf(hv.w) << 16);
        hb[i0 + lane] = o;
#pragma unroll
        for (int e = 0; e < NEXP; ++e) {
            float4 rv = reinterpret_cast<const float4*>(rw + e * HDIM)[i0 + lane];
            acc[e] += hv.x * rv.x + hv.y * rv.y + hv.z * rv.z + hv.w * rv.w;
        }
    }
#pragma unroll
    for (int e = 0; e < NEXP; ++e) {
#pragma unroll
        for (int off = 32; off > 0; off >>= 1)
            acc[e] += __shfl_xor(acc[e], off);
    }
    if (lane == 0) {
        int i0 = 0; float m0 = acc[0];
        for (int e = 1; e < NEXP; ++e) if (acc[e] > m0) { m0 = acc[e]; i0 = e; }
        int i1 = -1; float m1 = -3.0e38f;
        for (int e = 0; e < NEXP; ++e) if (e != i0 && acc[e] > m1) { m1 = acc[e]; i1 = e; }
        float d  = __expf(m1 - m0);
        float w0 = 1.f / (1.f + d);
        topk_idx[n * 2 + 0] = i0;
        topk_idx[n * 2 + 1] = i1;
        topk_w [n * 2 + 0] = w0;
        topk_w [n * 2 + 1] = 1.f - w0;
    }
}

// ---------------------------------------------------------------------------
// Counting-sort permutation + 128-row tile table.
__global__ __launch_bounds__(256) void k_build_perm(
    const int* __restrict__ topk_idx, const float* __restrict__ topk_w,
    int* __restrict__ offsets, int* __restrict__ perm_slot, float* __restrict__ row_w,
    int* __restrict__ tile_e, int* __restrict__ tile_rt)
{
    __shared__ int cnt[NEXP];
    __shared__ int cur[NEXP];
    __shared__ int off[NEXP + 1];
    const int t = threadIdx.x;
    if (t < NEXP) cnt[t] = 0;
    __syncthreads();
    for (int s = t; s < NKROWS; s += 256) atomicAdd(&cnt[topk_idx[s]], 1);
    __syncthreads();
    if (t == 0) {
        int a = 0;
        for (int e = 0; e < NEXP; ++e) { off[e] = a; a += cnt[e]; cur[e] = off[e]; }
        off[NEXP] = a;
        int nt = 0;
        for (int e = 0; e < NEXP; ++e) {
            int ne = cnt[e];
            for (int r = 0; r * 128 < ne; ++r) { tile_e[nt] = e; tile_rt[nt] = r; ++nt; }
        }
        for (; nt < MAXTILES; ++nt) { tile_e[nt] = -1; tile_rt[nt] = 0; }
    }
    __syncthreads();
    for (int s = t; s < NKROWS; s += 256) {
        int e = topk_idx[s];
        int pos = atomicAdd(&cur[e], 1);
        perm_slot[pos] = s;
        row_w[pos] = topk_w[s];
    }
    if (t < NEXP + 1) offsets[t] = off[t];
}

// ---------------------------------------------------------------------------
// GEMM1: act[p][f] = silu(gate)*up. Block tile 128 rows x 64 f-cols (gate AND
// up). 4 waves (2x2): wave = 64r x (32g + 32u). dbuf LDS, 1 barrier/step.
__global__ __launch_bounds__(256, 2) void k_gemm1(
    const unsigned short* __restrict__ hbf, const float* __restrict__ gu,
    const int* __restrict__ offsets, const int* __restrict__ perm_slot,
    const int* __restrict__ tile_e, const int* __restrict__ tile_rt,
    unsigned short* __restrict__ act)
{
    const int e = tile_e[blockIdx.y];
    if (e < 0) return;
    const int rt = tile_rt[blockIdx.y];
    const int off_e = offsets[e];
    const int n_e   = offsets[e + 1] - off_e;
    const int p0 = off_e + rt * 128;
    const int nr = min(128, n_e - rt * 128);
    const int c0 = blockIdx.x * 64;

    __shared__ __align__(16) char smA [2][128 * 128];   // bf16 128r x 64K
    __shared__ __align__(16) char smBg[2][64 * 128];    // bf16 64c x 64K
    __shared__ __align__(16) char smBu[2][64 * 128];
    __shared__ int sTok[128];

    const int t = threadIdx.x;
    const int lane = t & 63;
    const int wv = t >> 6;
    const int wr = wv >> 1, wc = wv & 1;
    if (t < 128) sTok[t] = perm_slot[min(p0 + t, NKROWS - 1)] >> 1;
    __syncthreads();

    // A-DMA: chunk ch = wv*4+c covers rows ch*8..+8 (128B bf16 each), source
    // pre-swizzled so linear LDS dest holds the swizzled layout.
    const char* asrc[4];
    int aldo[4];
#pragma unroll
    for (int c = 0; c < 4; ++c) {
        int ch = wv * 4 + c;
        int rin = lane >> 3;
        int row = ch * 8 + rin;
        asrc[c] = (const char*)(hbf + (size_t)sTok[row] * HDIM)
                + ((((lane & 7) << 4) ^ (rin << 4)));
        aldo[c] = ch * 1024;
    }

    // B reg-staging: thread t owns virtual row vr (0..63 gate, 64..127 up),
    // K-half kh (32 floats = 64B bf16).
    const int vr = t >> 1;
    const int kh = t & 1;
    const int brow = vr & 63;
    const float* guE = gu + (size_t)e * (2 * FDIM) * HDIM;
    const float* bsrc = guE
        + (size_t)(vr < 64 ? c0 + vr : FDIM + c0 + (vr - 64)) * HDIM + kh * 32;
    const int bswz = (brow & 7) << 4;
    const int bo = kh * 64;

    floatx4 accg[4][2], accu[4][2];
#pragma unroll
    for (int m = 0; m < 4; ++m)
#pragma unroll
        for (int nn = 0; nn < 2; ++nn) { accg[m][nn] = (floatx4)0.f; accu[m][nn] = (floatx4)0.f; }

    // ---- prologue: stage step 0 into buf 0
#pragma unroll
    for (int c = 0; c < 4; ++c) dma16(asrc[c], &smA[0][aldo[c]]);
    {
        const float4* bp = reinterpret_cast<const float4*>(bsrc);
        float4 bv[8];
#pragma unroll
        for (int q = 0; q < 8; ++q) bv[q] = bp[q];
        char* dst = (vr < 64 ? smBg[0] : smBu[0]) + brow * 128;
        *reinterpret_cast<uint4*>(dst + ((bo     ) ^ bswz)) = pack8(bv[0], bv[1]);
        *reinterpret_cast<uint4*>(dst + ((bo + 16) ^ bswz)) = pack8(bv[2], bv[3]);
        *reinterpret_cast<uint4*>(dst + ((bo + 32) ^ bswz)) = pack8(bv[4], bv[5]);
        *reinterpret_cast<uint4*>(dst + ((bo + 48) ^ bswz)) = pack8(bv[6], bv[7]);
    }
    __syncthreads();

    int cur = 0;
    for (int step = 0; step < 16; ++step) {
        float4 bv[8];
        if (step < 15) {                       // issue t+1 traffic BEFORE compute
            const int k1 = (step + 1) * 64;
#pragma unroll
            for (int c = 0; c < 4; ++c) dma16(asrc[c] + (size_t)k1 * 2, &smA[cur ^ 1][aldo[c]]);
            const float4* bp = reinterpret_cast<const float4*>(bsrc + k1);
#pragma unroll
            for (int q = 0; q < 8; ++q) bv[q] = bp[q];
        }
        // ---- compute current buffer
#pragma unroll
        for (int kk = 0; kk < 2; ++kk) {
            const int kA = kk * 64 + (lane >> 4) * 16;
            bf16x8 a[4], fg[2], fu[2];
#pragma unroll
            for (int m = 0; m < 4; ++m) {
                int row = wr * 64 + m * 16 + (lane & 15);
                a[m] = *reinterpret_cast<const bf16x8*>(&smA[cur][row * 128 + (kA ^ ((row & 7) << 4))]);
            }
#pragma unroll
            for (int nn = 0; nn < 2; ++nn) {
                int cc = wc * 32 + nn * 16 + (lane & 15);
                int ad = cc * 128 + (kA ^ ((cc & 7) << 4));
                fg[nn] = *reinterpret_cast<const bf16x8*>(&smBg[cur][ad]);
                fu[nn] = *reinterpret_cast<const bf16x8*>(&smBu[cur][ad]);
            }
#pragma unroll
            for (int m = 0; m < 4; ++m)
#pragma unroll
                for (int nn = 0; nn < 2; ++nn) {
                    accg[m][nn] = __builtin_amdgcn_mfma_f32_16x16x32_bf16(a[m], fg[nn], accg[m][nn], 0, 0, 0);
                    accu[m][nn] = __builtin_amdgcn_mfma_f32_16x16x32_bf16(a[m], fu[nn], accu[m][nn], 0, 0, 0);
                }
        }
        if (step < 15) {                       // cvt + commit AFTER compute
            char* dst = (vr < 64 ? smBg[cur ^ 1] : smBu[cur ^ 1]) + brow * 128;
            *reinterpret_cast<uint4*>(dst + ((bo     ) ^ bswz)) = pack8(bv[0], bv[1]);
            *reinterpret_cast<uint4*>(dst + ((bo + 16) ^ bswz)) = pack8(bv[2], bv[3]);
            *reinterpret_cast<uint4*>(dst + ((bo + 32) ^ bswz)) = pack8(bv[4], bv[5]);
            *reinterpret_cast<uint4*>(dst + ((bo + 48) ^ bswz)) = pack8(bv[6], bv[7]);
        }
        __syncthreads();
        cur ^= 1;
    }

    // epilogue: silu(gate) * up -> act (bf16)
#pragma unroll
    for (int m = 0; m < 4; ++m)
#pragma unroll
        for (int nn = 0; nn < 2; ++nn)
#pragma unroll
            for (int j = 0; j < 4; ++j) {
                int rr = wr * 64 + m * 16 + ((lane >> 4) << 2) + j;
                if (rr < nr) {
                    int f = c0 + wc * 32 + nn * 16 + (lane & 15);
                    float gg = accg[m][nn][j];
                    float uu = accu[m][nn][j];
                    float s = gg / (1.f + __expf(-gg));
                    act[(size_t)(p0 + rr) * FDIM + f] = f2bf(s * uu);
                }
            }
}

// ---------------------------------------------------------------------------
// GEMM2: partial[slot][h] = w * (act_row . dp[e][h][:]), bf16 out.
// Block tile 128 rows x 128 h-cols; 4 waves (2x2), wave = 64x64, acc[4][4].
__global__ __launch_bounds__(256, 2) void k_gemm2(
    const unsigned short* __restrict__ act, const float* __restrict__ dp,
    const int* __restrict__ offsets, const int* __restrict__ perm_slot,
    const int* __restrict__ tile_e, const int* __restrict__ tile_rt,
    const float* __restrict__ row_w, unsigned short* __restrict__ partial)
{
    const int e = tile_e[blockIdx.y];
    if (e < 0) return;
    const int rt = tile_rt[blockIdx.y];
    const int off_e = offsets[e];
    const int n_e   = offsets[e + 1] - off_e;
    const int p0 = off_e + rt * 128;
    const int nr = min(128, n_e - rt * 128);
    const int c0 = blockIdx.x * 128;

    __shared__ __align__(16) char smA[2][128 * 128];
    __shared__ __align__(16) char smB[2][128 * 128];
    __shared__ int   sSlot[128];
    __shared__ float sW[128];

    const int t = threadIdx.x;
    const int lane = t & 63;
    const int wv = t >> 6;
    const int wr = wv >> 1, wc = wv & 1;
    if (t < 128) {
        int p = min(p0 + t, NKROWS - 1);
        sSlot[t] = perm_slot[p];
        sW[t]    = row_w[p];
    }
    // A rows are contiguous in act (already permuted) -> no gather, no barrier
    const char* asrc[4];
    int aldo[4];
#pragma unroll
    for (int c = 0; c < 4; ++c) {
        int ch = wv * 4 + c;
        int rin = lane >> 3;
        int row = ch * 8 + rin;
        int p = min(p0 + row, NKROWS - 1);
        asrc[c] = (const char*)(act + (size_t)p * FDIM)
                + ((((lane & 7) << 4) ^ (rin << 4)));
        aldo[c] = ch * 1024;
    }

    const int vr = t >> 1;      // B row = h-col c0+vr
    const int kh = t & 1;
    const float* bsrc = dp + (size_t)e * HDIM * FDIM + (size_t)(c0 + vr) * FDIM + kh * 32;
    const int bswz = (vr & 7) << 4;
    const int bo = kh * 64;

    floatx4 acc[4][4];
#pragma unroll
    for (int m = 0; m < 4; ++m)
#pragma unroll
        for (int nn = 0; nn < 4; ++nn) acc[m][nn] = (floatx4)0.f;

    // prologue
#pragma unroll
    for (int c = 0; c < 4; ++c) dma16(asrc[c], &smA[0][aldo[c]]);
    {
        const float4* bp = reinterpret_cast<const float4*>(bsrc);
        float4 bv[8];
#pragma unroll
        for (int q = 0; q < 8; ++q) bv[q] = bp[q];
        char* dst = smB[0] + vr * 128;
        *reinterpret_cast<uint4*>(dst + ((bo     ) ^ bswz)) = pack8(bv[0], bv[1]);
        *reinterpret_cast<uint4*>(dst + ((bo + 16) ^ bswz)) = pack8(bv[2], bv[3]);
        *reinterpret_cast<uint4*>(dst + ((bo + 32) ^ bswz)) = pack8(bv[4], bv[5]);
        *reinterpret_cast<uint4*>(dst + ((bo + 48) ^ bswz)) = pack8(bv[6], bv[7]);
    }
    __syncthreads();

    int cur = 0;
    for (int step = 0; step < 16; ++step) {
        float4 bv[8];
        if (step < 15) {
            const int k1 = (step + 1) * 64;
#pragma unroll
            for (int c = 0; c < 4; ++c) dma16(asrc[c] + (size_t)k1 * 2, &smA[cur ^ 1][aldo[c]]);
            const float4* bp = reinterpret_cast<const float4*>(bsrc + k1);
#pragma unroll
            for (int q = 0; q < 8; ++q) bv[q] = bp[q];
        }
#pragma unroll
        for (int kk = 0; kk < 2; ++kk) {
            const int kA = kk * 64 + (lane >> 4) * 16;
            bf16x8 a[4], fb[4];
#pragma unroll
            for (int m = 0; m < 4; ++m) {
                int row = wr * 64 + m * 16 + (lane & 15);
                a[m] = *reinterpret_cast<const bf16x8*>(&smA[cur][row * 128 + (kA ^ ((row & 7) << 4))]);
            }
#pragma unroll
            for (int nn = 0; nn < 4; ++nn) {
                int cc = wc * 64 + nn * 16 + (lane & 15);
                fb[nn] = *reinterpret_cast<const bf16x8*>(&smB[cur][cc * 128 + (kA ^ ((cc & 7) << 4))]);
            }
#pragma unroll
            for (int m = 0; m < 4; ++m)
#pragma unroll
                for (int nn = 0; nn < 4; ++nn)
                    acc[m][nn] = __builtin_amdgcn_mfma_f32_16x16x32_bf16(a[m], fb[nn], acc[m][nn], 0, 0, 0);
        }
        if (step < 15) {
            char* dst = smB[cur ^ 1] + vr * 128;
            *reinterpret_cast<uint4*>(dst + ((bo     ) ^ bswz)) = pack8(bv[0], bv[1]);
            *reinterpret_cast<uint4*>(dst + ((bo + 16) ^ bswz)) = pack8(bv[2], bv[3]);
            *reinterpret_cast<uint4*>(dst + ((bo + 32) ^ bswz)) = pack8(bv[4], bv[5]);
            *reinterpret_cast<uint4*>(dst + ((bo + 48) ^ bswz)) = pack8(bv[6], bv[7]);
        }
        __syncthreads();
        cur ^= 1;
    }

#pragma unroll
    for (int m = 0; m < 4; ++m)
#pragma unroll
        for (int nn = 0; nn < 4; ++nn)
#pragma unroll
            for (int j = 0; j < 4; ++j) {
                int rr = wr * 64 + m * 16 + ((lane >> 4) << 2) + j;
                if (rr < nr) {
                    int hcol = c0 + wc * 64 + nn * 16 + (lane & 15);
                    partial[(size_t)sSlot[rr] * HDIM + hcol] = f2bf(sW[rr] * acc[m][nn][j]);
                }
            }
}

// ---------------------------------------------------------------------------
// out[n][h] = partial[2n][h] + partial[2n+1][h]  (bf16 -> fp32)
__global__ __launch_bounds__(256) void k_combine(
    const unsigned short* __restrict__ partial, float* __restrict__ out)
{
    int gid = blockIdx.x * 256 + threadIdx.x;   // NTOK * H / 8 = 262144
    int n = gid >> 7;
    int r = gid & 127;
    uint4 a = reinterpret_cast<const uint4*>(partial + (size_t)(2 * n) * HDIM)[r];
    uint4 b = reinterpret_cast<const uint4*>(partial + (size_t)(2 * n + 1) * HDIM)[r];
    float4 o0, o1;
    o0.x = bf2f(a.x & 0xFFFF) + bf2f(b.x & 0xFFFF);
    o0.y = bf2f(a.x >> 16)    + bf2f(b.x >> 16);
    o0.z = bf2f(a.y & 0xFFFF) + bf2f(b.y & 0xFFFF);
    o0.w = bf2f(a.y >> 16)    + bf2f(b.y >> 16);
    o1.x = bf2f(a.z & 0xFFFF) + bf2f(b.z & 0xFFFF);
    o1.y = bf2f(a.z >> 16)    + bf2f(b.z >> 16);
    o1.z = bf2f(a.w & 0xFFFF) + bf2f(b.w & 0xFFFF);
    o1.w = bf2f(a.w >> 16)    + bf2f(b.w >> 16);
    float4* op = reinterpret_cast<float4*>(out + (size_t)n * HDIM + r * 8);
    op[0] = o0;
    op[1] = o1;
}

// ---------------------------------------------------------------------------
extern "C" void kernel_launch(void* const* d_in, const int* in_sizes, int n_in,
                              void* d_out, int out_size, void* d_ws, size_t ws_size,
                              hipStream_t stream)
{
    const float* h  = (const float*)d_in[0];
    const float* rw = (const float*)d_in[1];
    const float* gu = (const float*)d_in[2];
    const float* dp = (const float*)d_in[3];
    float* out = (float*)d_out;

    char* ws = (char*)d_ws;
    int*            topk_idx  = (int*)   (ws + 0);
    float*          topk_w    = (float*) (ws + 16384);
    int*            offsets   = (int*)   (ws + 32768);
    int*            tile_e    = (int*)   (ws + 33024);
    int*            tile_rt   = (int*)   (ws + 33280);
    int*            perm_slot = (int*)   (ws + 36864);
    float*          row_w     = (float*) (ws + 53248);
    unsigned short* hbf       = (unsigned short*)(ws + (1u << 20));
    unsigned short* act       = (unsigned short*)(ws + (8u << 20));
    unsigned short* partial   = (unsigned short*)(ws + (16u << 20));

    hipLaunchKernelGGL(k_router,     dim3(512), dim3(256), 0, stream, h, rw, hbf, topk_idx, topk_w);
    hipLaunchKernelGGL(k_build_perm, dim3(1),   dim3(256), 0, stream, topk_idx, topk_w, offsets, perm_slot, row_w, tile_e, tile_rt);
    hipLaunchKernelGGL(k_gemm1,      dim3(16, MAXTILES), dim3(256), 0, stream, hbf, gu, offsets, perm_slot, tile_e, tile_rt, act);
    hipLaunchKernelGGL(k_gemm2,      dim3(8,  MAXTILES), dim3(256), 0, stream, act, dp, offsets, perm_slot, tile_e, tile_rt, row_w, partial);
    hipLaunchKernelGGL(k_combine,    dim3(1024), dim3(256), 0, stream, partial, out);
}

// Round 5
// 99.971 us; speedup vs baseline: 1.6317x; 1.6317x over previous
//
#include <hip/hip_runtime.h>

// ---------------------------------------------------------------------------
// FakeFusedMoE: E=8, H=1024, F=1024, top-2, N=2048 tokens (4096 routed rows).
// Sparse grouped-GEMM MoE, bf16 MFMA.
//   k_convert_w : fp32 weights (gu, dp) -> bf16 copies, streaming at HBM BW
//   k_router    : logits -> top2 (analytic renorm) + hidden fp32->bf16
//   k_build_perm: counting-sort rows by expert + tile table
//   k_gemm1/2   : R3-proven structure: single-buffer LDS, 2 barriers/K-step,
//                 ALL operands bf16 via global_load_lds (pre-swizzled source)
//   k_combine   : out[n] = partial[2n] + partial[2n+1]
// ---------------------------------------------------------------------------

#define NTOK   2048
#define HDIM   1024
#define FDIM   1024
#define NEXP   8
#define NKROWS 4096
#define MAXTILES 40   // sum ceil(n_e/128) <= 39

typedef __attribute__((ext_vector_type(8))) __bf16 bf16x8;
typedef __attribute__((ext_vector_type(4))) float  floatx4;

__device__ __forceinline__ unsigned short f2bf(float x) {
    unsigned int u = __builtin_bit_cast(unsigned int, x);
    u += 0x7FFFu + ((u >> 16) & 1u);
    return (unsigned short)(u >> 16);
}

__device__ __forceinline__ float bf2f(unsigned short v) {
    unsigned int u = (unsigned int)v << 16;
    return __builtin_bit_cast(float, u);
}

__device__ __forceinline__ uint4 pack8(float4 a, float4 b) {
    uint4 o;
    o.x = (unsigned)f2bf(a.x) | ((unsigned)f2bf(a.y) << 16);
    o.y = (unsigned)f2bf(a.z) | ((unsigned)f2bf(a.w) << 16);
    o.z = (unsigned)f2bf(b.x) | ((unsigned)f2bf(b.y) << 16);
    o.w = (unsigned)f2bf(b.z) | ((unsigned)f2bf(b.w) << 16);
    return o;
}

// async global->LDS, 16B/lane; LDS dest = wave-uniform base + lane*16
__device__ __forceinline__ void dma16(const void* g, void* l) {
    __builtin_amdgcn_global_load_lds(
        (const __attribute__((address_space(1))) unsigned int*)g,
        (__attribute__((address_space(3))) unsigned int*)l, 16, 0, 0);
}

// ---------------------------------------------------------------------------
// Streaming fp32 -> bf16 conversion of gate_up_proj and down_proj.
__global__ __launch_bounds__(256) void k_convert_w(
    const float* __restrict__ gu, const float* __restrict__ dp,
    unsigned short* __restrict__ gubf, unsigned short* __restrict__ dpbf)
{
    const size_t GUE = (size_t)NEXP * 2 * FDIM * HDIM;          // 16777216
    const size_t TOT = GUE + (size_t)NEXP * HDIM * FDIM;        // 25165824
    size_t i = ((size_t)blockIdx.x * 256 + threadIdx.x) * 8;
    const size_t stride = (size_t)2048 * 256 * 8;
    for (; i < TOT; i += stride) {
        const float4* s;
        unsigned short* d;
        if (i < GUE) { s = reinterpret_cast<const float4*>(gu + i);        d = gubf + i; }
        else         { s = reinterpret_cast<const float4*>(dp + (i - GUE)); d = dpbf + (i - GUE); }
        float4 a = s[0], b = s[1];
        *reinterpret_cast<uint4*>(d) = pack8(a, b);
    }
}

// ---------------------------------------------------------------------------
// Router fused with fp32->bf16 hidden conversion. One wave per token.
__global__ __launch_bounds__(256) void k_router(
    const float* __restrict__ h, const float* __restrict__ rw,
    unsigned short* __restrict__ hbf,
    int* __restrict__ topk_idx, float* __restrict__ topk_w)
{
    const int lane = threadIdx.x & 63;
    const int wave = threadIdx.x >> 6;
    const int n = blockIdx.x * 4 + wave;

    const float4* hp = reinterpret_cast<const float4*>(h + (size_t)n * HDIM);
    uint2* hb = reinterpret_cast<uint2*>(hbf + (size_t)n * HDIM);
    float acc[NEXP];
#pragma unroll
    for (int e = 0; e < NEXP; ++e) acc[e] = 0.f;

#pragma unroll
    for (int i0 = 0; i0 < HDIM / 4; i0 += 64) {
        float4 hv = hp[i0 + lane];
        uint2 o;
        o.x = (unsigned)f2bf(hv.x) | ((unsigned)f2bf(hv.y) << 16);
        o.y = (unsigned)f2bf(hv.z) | ((unsigned)f2bf(hv.w) << 16);
        hb[i0 + lane] = o;
#pragma unroll
        for (int e = 0; e < NEXP; ++e) {
            float4 rv = reinterpret_cast<const float4*>(rw + e * HDIM)[i0 + lane];
            acc[e] += hv.x * rv.x + hv.y * rv.y + hv.z * rv.z + hv.w * rv.w;
        }
    }
#pragma unroll
    for (int e = 0; e < NEXP; ++e) {
#pragma unroll
        for (int off = 32; off > 0; off >>= 1)
            acc[e] += __shfl_xor(acc[e], off);
    }
    if (lane == 0) {
        int i0 = 0; float m0 = acc[0];
        for (int e = 1; e < NEXP; ++e) if (acc[e] > m0) { m0 = acc[e]; i0 = e; }
        int i1 = -1; float m1 = -3.0e38f;
        for (int e = 0; e < NEXP; ++e) if (e != i0 && acc[e] > m1) { m1 = acc[e]; i1 = e; }
        float d  = __expf(m1 - m0);
        float w0 = 1.f / (1.f + d);
        topk_idx[n * 2 + 0] = i0;
        topk_idx[n * 2 + 1] = i1;
        topk_w [n * 2 + 0] = w0;
        topk_w [n * 2 + 1] = 1.f - w0;
    }
}

// ---------------------------------------------------------------------------
// Counting-sort permutation + 128-row tile table.
__global__ __launch_bounds__(256) void k_build_perm(
    const int* __restrict__ topk_idx, const float* __restrict__ topk_w,
    int* __restrict__ offsets, int* __restrict__ perm_slot, float* __restrict__ row_w,
    int* __restrict__ tile_e, int* __restrict__ tile_rt)
{
    __shared__ int cnt[NEXP];
    __shared__ int cur[NEXP];
    __shared__ int off[NEXP + 1];
    const int t = threadIdx.x;
    if (t < NEXP) cnt[t] = 0;
    __syncthreads();
    for (int s = t; s < NKROWS; s += 256) atomicAdd(&cnt[topk_idx[s]], 1);
    __syncthreads();
    if (t == 0) {
        int a = 0;
        for (int e = 0; e < NEXP; ++e) { off[e] = a; a += cnt[e]; cur[e] = off[e]; }
        off[NEXP] = a;
        int nt = 0;
        for (int e = 0; e < NEXP; ++e) {
            int ne = cnt[e];
            for (int r = 0; r * 128 < ne; ++r) { tile_e[nt] = e; tile_rt[nt] = r; ++nt; }
        }
        for (; nt < MAXTILES; ++nt) { tile_e[nt] = -1; tile_rt[nt] = 0; }
    }
    __syncthreads();
    for (int s = t; s < NKROWS; s += 256) {
        int e = topk_idx[s];
        int pos = atomicAdd(&cur[e], 1);
        perm_slot[pos] = s;
        row_w[pos] = topk_w[s];
    }
    if (t < NEXP + 1) offsets[t] = off[t];
}

// ---------------------------------------------------------------------------
// GEMM1: act[p][f] = silu(gate)*up. Block 128 rows x 64 f-cols (gate AND up).
// 4 waves (2x2): wave = 64r x (32g+32u). Single-buffer, 2 barriers/step,
// all operands bf16 via DMA. LDS 32KB -> 4 blocks/CU.
__global__ __launch_bounds__(256, 4) void k_gemm1(
    const unsigned short* __restrict__ hbf, const unsigned short* __restrict__ gubf,
    const int* __restrict__ offsets, const int* __restrict__ perm_slot,
    const int* __restrict__ tile_e, const int* __restrict__ tile_rt,
    unsigned short* __restrict__ act)
{
    const int e = tile_e[blockIdx.y];
    if (e < 0) return;
    const int rt = tile_rt[blockIdx.y];
    const int off_e = offsets[e];
    const int n_e   = offsets[e + 1] - off_e;
    const int p0 = off_e + rt * 128;
    const int nr = min(128, n_e - rt * 128);
    const int c0 = blockIdx.x * 64;

    __shared__ __align__(16) char smA [128 * 128];   // bf16 128r x 64K
    __shared__ __align__(16) char smBg[64 * 128];    // bf16 64c x 64K
    __shared__ __align__(16) char smBu[64 * 128];
    __shared__ int sTok[128];

    const int t = threadIdx.x;
    const int lane = t & 63;
    const int wv = t >> 6;
    const int wr = wv >> 1, wc = wv & 1;
    if (t < 128) sTok[t] = perm_slot[min(p0 + t, NKROWS - 1)] >> 1;
    __syncthreads();

    const int rin = lane >> 3;
    const int pre = ((lane & 7) << 4) ^ (rin << 4);   // pre-swizzled source byte

    // A-DMA: chunk ch = wv*4+c covers rows ch*8..+8 (128B bf16 each)
    const char* asrc[4];
    int aldo[4];
#pragma unroll
    for (int c = 0; c < 4; ++c) {
        int ch = wv * 4 + c;
        int row = ch * 8 + rin;
        asrc[c] = (const char*)(hbf + (size_t)sTok[row] * HDIM) + pre;
        aldo[c] = ch * 1024;
    }
    // B-DMA: gate/up chunks, ch = wv*2+c covers cols ch*8..+8
    const unsigned short* guE = gubf + (size_t)e * (2 * FDIM) * HDIM;
    const char* gsrc[2];
    const char* usrc[2];
    int bldo[2];
#pragma unroll
    for (int c = 0; c < 2; ++c) {
        int ch = wv * 2 + c;
        int col = ch * 8 + rin;
        gsrc[c] = (const char*)(guE + (size_t)(c0 + col) * HDIM) + pre;
        usrc[c] = (const char*)(guE + (size_t)(FDIM + c0 + col) * HDIM) + pre;
        bldo[c] = ch * 1024;
    }

    floatx4 accg[4][2], accu[4][2];
#pragma unroll
    for (int m = 0; m < 4; ++m)
#pragma unroll
        for (int nn = 0; nn < 2; ++nn) { accg[m][nn] = (floatx4)0.f; accu[m][nn] = (floatx4)0.f; }

    for (int k0 = 0; k0 < HDIM; k0 += 64) {
        if (k0) __syncthreads();
#pragma unroll
        for (int c = 0; c < 4; ++c) dma16(asrc[c] + (size_t)k0 * 2, smA  + aldo[c]);
#pragma unroll
        for (int c = 0; c < 2; ++c) dma16(gsrc[c] + (size_t)k0 * 2, smBg + bldo[c]);
#pragma unroll
        for (int c = 0; c < 2; ++c) dma16(usrc[c] + (size_t)k0 * 2, smBu + bldo[c]);
        __syncthreads();
#pragma unroll
        for (int kk = 0; kk < 2; ++kk) {
            const int kA = kk * 64 + (lane >> 4) * 16;
            bf16x8 a[4], fg[2], fu[2];
#pragma unroll
            for (int m = 0; m < 4; ++m) {
                int row = wr * 64 + m * 16 + (lane & 15);
                a[m] = *reinterpret_cast<const bf16x8*>(smA + row * 128 + (kA ^ ((row & 7) << 4)));
            }
#pragma unroll
            for (int nn = 0; nn < 2; ++nn) {
                int cc = wc * 32 + nn * 16 + (lane & 15);
                int ad = cc * 128 + (kA ^ ((cc & 7) << 4));
                fg[nn] = *reinterpret_cast<const bf16x8*>(smBg + ad);
                fu[nn] = *reinterpret_cast<const bf16x8*>(smBu + ad);
            }
#pragma unroll
            for (int m = 0; m < 4; ++m)
#pragma unroll
                for (int nn = 0; nn < 2; ++nn) {
                    accg[m][nn] = __builtin_amdgcn_mfma_f32_16x16x32_bf16(a[m], fg[nn], accg[m][nn], 0, 0, 0);
                    accu[m][nn] = __builtin_amdgcn_mfma_f32_16x16x32_bf16(a[m], fu[nn], accu[m][nn], 0, 0, 0);
                }
        }
    }

    // epilogue: silu(gate) * up -> act (bf16)
#pragma unroll
    for (int m = 0; m < 4; ++m)
#pragma unroll
        for (int nn = 0; nn < 2; ++nn)
#pragma unroll
            for (int j = 0; j < 4; ++j) {
                int rr = wr * 64 + m * 16 + ((lane >> 4) << 2) + j;
                if (rr < nr) {
                    int f = c0 + wc * 32 + nn * 16 + (lane & 15);
                    float gg = accg[m][nn][j];
                    float uu = accu[m][nn][j];
                    float s = gg / (1.f + __expf(-gg));
                    act[(size_t)(p0 + rr) * FDIM + f] = f2bf(s * uu);
                }
            }
}

// ---------------------------------------------------------------------------
// GEMM2: partial[slot][h] = w * (act_row . dp[e][h][:]), bf16 out.
// Block 128 rows x 128 h-cols; 4 waves (2x2), wave 64x64, acc[4][4].
__global__ __launch_bounds__(256, 4) void k_gemm2(
    const unsigned short* __restrict__ act, const unsigned short* __restrict__ dpbf,
    const int* __restrict__ offsets, const int* __restrict__ perm_slot,
    const int* __restrict__ tile_e, const int* __restrict__ tile_rt,
    const float* __restrict__ row_w, unsigned short* __restrict__ partial)
{
    const int e = tile_e[blockIdx.y];
    if (e < 0) return;
    const int rt = tile_rt[blockIdx.y];
    const int off_e = offsets[e];
    const int n_e   = offsets[e + 1] - off_e;
    const int p0 = off_e + rt * 128;
    const int nr = min(128, n_e - rt * 128);
    const int c0 = blockIdx.x * 128;

    __shared__ __align__(16) char smA[128 * 128];
    __shared__ __align__(16) char smB[128 * 128];
    __shared__ int   sSlot[128];
    __shared__ float sW[128];

    const int t = threadIdx.x;
    const int lane = t & 63;
    const int wv = t >> 6;
    const int wr = wv >> 1, wc = wv & 1;
    if (t < 128) {
        int p = min(p0 + t, NKROWS - 1);
        sSlot[t] = perm_slot[p];
        sW[t]    = row_w[p];
    }

    const int rin = lane >> 3;
    const int pre = ((lane & 7) << 4) ^ (rin << 4);

    // A: act rows are contiguous (already permuted)
    const char* asrc[4];
    int aldo[4];
#pragma unroll
    for (int c = 0; c < 4; ++c) {
        int ch = wv * 4 + c;
        int row = ch * 8 + rin;
        int p = min(p0 + row, NKROWS - 1);
        asrc[c] = (const char*)(act + (size_t)p * FDIM) + pre;
        aldo[c] = ch * 1024;
    }
    // B: dpbf rows = output h-cols
    const unsigned short* dpE = dpbf + (size_t)e * HDIM * FDIM;
    const char* bsrc[4];
    int bldo[4];
#pragma unroll
    for (int c = 0; c < 4; ++c) {
        int ch = wv * 4 + c;
        int col = ch * 8 + rin;
        bsrc[c] = (const char*)(dpE + (size_t)(c0 + col) * FDIM) + pre;
        bldo[c] = ch * 1024;
    }

    floatx4 acc[4][4];
#pragma unroll
    for (int m = 0; m < 4; ++m)
#pragma unroll
        for (int nn = 0; nn < 4; ++nn) acc[m][nn] = (floatx4)0.f;

    for (int k0 = 0; k0 < FDIM; k0 += 64) {
        __syncthreads();                     // also covers sSlot/sW fill
#pragma unroll
        for (int c = 0; c < 4; ++c) dma16(asrc[c] + (size_t)k0 * 2, smA + aldo[c]);
#pragma unroll
        for (int c = 0; c < 4; ++c) dma16(bsrc[c] + (size_t)k0 * 2, smB + bldo[c]);
        __syncthreads();
#pragma unroll
        for (int kk = 0; kk < 2; ++kk) {
            const int kA = kk * 64 + (lane >> 4) * 16;
            bf16x8 a[4], fb[4];
#pragma unroll
            for (int m = 0; m < 4; ++m) {
                int row = wr * 64 + m * 16 + (lane & 15);
                a[m] = *reinterpret_cast<const bf16x8*>(smA + row * 128 + (kA ^ ((row & 7) << 4)));
            }
#pragma unroll
            for (int nn = 0; nn < 4; ++nn) {
                int cc = wc * 64 + nn * 16 + (lane & 15);
                fb[nn] = *reinterpret_cast<const bf16x8*>(smB + cc * 128 + (kA ^ ((cc & 7) << 4)));
            }
#pragma unroll
            for (int m = 0; m < 4; ++m)
#pragma unroll
                for (int nn = 0; nn < 4; ++nn)
                    acc[m][nn] = __builtin_amdgcn_mfma_f32_16x16x32_bf16(a[m], fb[nn], acc[m][nn], 0, 0, 0);
        }
    }

#pragma unroll
    for (int m = 0; m < 4; ++m)
#pragma unroll
        for (int nn = 0; nn < 4; ++nn)
#pragma unroll
            for (int j = 0; j < 4; ++j) {
                int rr = wr * 64 + m * 16 + ((lane >> 4) << 2) + j;
                if (rr < nr) {
                    int hcol = c0 + wc * 64 + nn * 16 + (lane & 15);
                    partial[(size_t)sSlot[rr] * HDIM + hcol] = f2bf(sW[rr] * acc[m][nn][j]);
                }
            }
}

// ---------------------------------------------------------------------------
// out[n][h] = partial[2n][h] + partial[2n+1][h]  (bf16 -> fp32)
__global__ __launch_bounds__(256) void k_combine(
    const unsigned short* __restrict__ partial, float* __restrict__ out)
{
    int gid = blockIdx.x * 256 + threadIdx.x;   // NTOK * H / 8 = 262144
    int n = gid >> 7;
    int r = gid & 127;
    uint4 a = reinterpret_cast<const uint4*>(partial + (size_t)(2 * n) * HDIM)[r];
    uint4 b = reinterpret_cast<const uint4*>(partial + (size_t)(2 * n + 1) * HDIM)[r];
    float4 o0, o1;
    o0.x = bf2f(a.x & 0xFFFF) + bf2f(b.x & 0xFFFF);
    o0.y = bf2f(a.x >> 16)    + bf2f(b.x >> 16);
    o0.z = bf2f(a.y & 0xFFFF) + bf2f(b.y & 0xFFFF);
    o0.w = bf2f(a.y >> 16)    + bf2f(b.y >> 16);
    o1.x = bf2f(a.z & 0xFFFF) + bf2f(b.z & 0xFFFF);
    o1.y = bf2f(a.z >> 16)    + bf2f(b.z >> 16);
    o1.z = bf2f(a.w & 0xFFFF) + bf2f(b.w & 0xFFFF);
    o1.w = bf2f(a.w >> 16)    + bf2f(b.w >> 16);
    float4* op = reinterpret_cast<float4*>(out + (size_t)n * HDIM + r * 8);
    op[0] = o0;
    op[1] = o1;
}

// ---------------------------------------------------------------------------
extern "C" void kernel_launch(void* const* d_in, const int* in_sizes, int n_in,
                              void* d_out, int out_size, void* d_ws, size_t ws_size,
                              hipStream_t stream)
{
    const float* h  = (const float*)d_in[0];
    const float* rw = (const float*)d_in[1];
    const float* gu = (const float*)d_in[2];
    const float* dp = (const float*)d_in[3];
    float* out = (float*)d_out;

    char* ws = (char*)d_ws;
    int*            topk_idx  = (int*)   (ws + 0);
    float*          topk_w    = (float*) (ws + 16384);
    int*            offsets   = (int*)   (ws + 32768);
    int*            tile_e    = (int*)   (ws + 33024);
    int*            tile_rt   = (int*)   (ws + 33280);
    int*            perm_slot = (int*)   (ws + 36864);
    float*          row_w     = (float*) (ws + 53248);
    unsigned short* hbf       = (unsigned short*)(ws + (1u  << 20));  // 8MB
    unsigned short* partial   = (unsigned short*)(ws + (1u  << 20));  // overlays hbf (dead after gemm1)
    unsigned short* act       = (unsigned short*)(ws + (9u  << 20));  // 8MB
    unsigned short* gubf      = (unsigned short*)(ws + (17u << 20));  // 32MB
    unsigned short* dpbf      = (unsigned short*)(ws + (49u << 20));  // 16MB

    hipLaunchKernelGGL(k_convert_w,  dim3(2048), dim3(256), 0, stream, gu, dp, gubf, dpbf);
    hipLaunchKernelGGL(k_router,     dim3(512),  dim3(256), 0, stream, h, rw, hbf, topk_idx, topk_w);
    hipLaunchKernelGGL(k_build_perm, dim3(1),    dim3(256), 0, stream, topk_idx, topk_w, offsets, perm_slot, row_w, tile_e, tile_rt);
    hipLaunchKernelGGL(k_gemm1,      dim3(16, MAXTILES), dim3(256), 0, stream, hbf, gubf, offsets, perm_slot, tile_e, tile_rt, act);
    hipLaunchKernelGGL(k_gemm2,      dim3(8,  MAXTILES), dim3(256), 0, stream, act, dpbf, offsets, perm_slot, tile_e, tile_rt, row_w, partial);
    hipLaunchKernelGGL(k_combine,    dim3(1024), dim3(256), 0, stream, partial, out);
}